// Round 12
// baseline (50.816 us; speedup 1.0000x reference)
//
#include <hip/hip_runtime.h>
#include <hip/hip_bf16.h>

typedef int   i32x4  __attribute__((ext_vector_type(4)));
typedef int   i32x16 __attribute__((ext_vector_type(16)));

#define NROWS 8192
#define DIM   128
#define NBW   128           // 8192 / 64 row-blocks (per-wave tiles)
#define JOBSW 8256          // 128*129/2 upper-tri incl diag (per matrix)

__device__ __forceinline__ float fast_exp2(float x) {
    return __builtin_amdgcn_exp2f(x);
}

__device__ __forceinline__ int tri128(int b) { return b * NBW - (b * (b - 1)) / 2; }

// ---------------------------------------------------------------------------
// Kernel 1: normalize rows (float4, 2 rows/wave), align partials (exact fp32),
// emit i8 quantized normalized rows: q = round(127 * x_hat).
// ---------------------------------------------------------------------------
__global__ __launch_bounds__(256) void prep_kernel(
    const float* __restrict__ users, const float* __restrict__ pos,
    signed char* __restrict__ U8, signed char* __restrict__ P8,
    double* __restrict__ alignPart)
{
    const int tid  = threadIdx.x;
    const int lane = tid & 63;
    const int w    = tid >> 6;
    const int l32  = lane & 31;
    const int half = lane >> 5;
    const int r    = blockIdx.x * 8 + w * 2 + half;

    const float4 u4 = ((const float4*)users)[r * 32 + l32];
    const float4 p4 = ((const float4*)pos )[r * 32 + l32];

    float su = u4.x*u4.x + u4.y*u4.y + u4.z*u4.z + u4.w*u4.w;
    float sp = p4.x*p4.x + p4.y*p4.y + p4.z*p4.z + p4.w*p4.w;
    for (int off = 16; off; off >>= 1) {
        su += __shfl_xor(su, off, 64);
        sp += __shfl_xor(sp, off, 64);
    }
    const float nu  = fmaxf(sqrtf(su), 1e-12f);
    const float npp = fmaxf(sqrtf(sp), 1e-12f);

    const float ux = u4.x / nu,  uy = u4.y / nu,  uz = u4.z / nu,  uw = u4.w / nu;
    const float px = p4.x / npp, py = p4.y / npp, pz = p4.z / npp, pw = p4.w / npp;

    union { signed char c[4]; int i; } qu, qp;
    qu.c[0] = (signed char)__float2int_rn(ux * 127.0f);
    qu.c[1] = (signed char)__float2int_rn(uy * 127.0f);
    qu.c[2] = (signed char)__float2int_rn(uz * 127.0f);
    qu.c[3] = (signed char)__float2int_rn(uw * 127.0f);
    qp.c[0] = (signed char)__float2int_rn(px * 127.0f);
    qp.c[1] = (signed char)__float2int_rn(py * 127.0f);
    qp.c[2] = (signed char)__float2int_rn(pz * 127.0f);
    qp.c[3] = (signed char)__float2int_rn(pw * 127.0f);
    ((int*)U8)[r * 32 + l32] = qu.i;
    ((int*)P8)[r * 32 + l32] = qp.i;

    const float dx = ux - px, dy = uy - py, dz = uz - pz, dw = uw - pw;
    float al = dx*dx + dy*dy + dz*dz + dw*dw;
    for (int off = 16; off; off >>= 1) al += __shfl_xor(al, off, 64);
    al += __shfl_xor(al, 32, 64);

    __shared__ float wsum[4];
    if (lane == 0) wsum[w] = al;
    __syncthreads();
    if (tid == 0)
        alignPart[blockIdx.x] = (double)wsum[0] + (double)wsum[1]
                              + (double)wsum[2] + (double)wsum[3];
}

// ---------------------------------------------------------------------------
// Kernel 2: BARRIER-FREE, LDS-FREE. One 64x64 tile per WAVE (bi<=bj over
// 64-row blocks; off-diag x2; diag tiles summed fully -> S_full identity
// unchanged). Each wave issues its 16 fragment loads (global_load_dwordx4,
// L1/L2-resident i8 data) up-front, MFMAs from registers as they land
// (counted vmcnt by compiler, no vmcnt(0) drain, no __syncthreads anywhere),
// then the exp epilogue. 12 waves/CU at naturally drifting phases overlap
// VMEM / MFMA / VALU / trans across waves (m114 mechanism).
// Block's 4 waves take consecutive tri jobs -> adjacent tiles -> L1 reuse.
// mfma_i32_32x32x32_i8 A/B fragment: lane l -> row (l&31), 16B k-chunk (l>>5).
// A and B use the identical gather from the same matrix, so any common
// permutation cancels in the Gram sum.
// ---------------------------------------------------------------------------
__global__ __launch_bounds__(256, 3) void gram_kernel(
    const signed char* __restrict__ U8, const signed char* __restrict__ P8,
    double* __restrict__ Spart)
{
    const int tid  = threadIdx.x;
    const int lane = tid & 63;
    const int wid  = blockIdx.x * 4 + (tid >> 6);   // global wave-job id

    const int mat = wid >= JOBSW;
    const int t   = wid - (mat ? JOBSW : 0);

    // decode upper-tri (bi, bj), NBW = 128
    int bi = (int)(128.5f - sqrtf(128.5f * 128.5f - 2.0f * (float)t));
    if (bi > 0 && tri128(bi) > t) --bi;
    if (tri128(bi + 1) <= t) ++bi;
    const int bj = bi + (t - tri128(bi));

    const char* __restrict__ Xb = (const char*)(mat ? P8 : U8);

    const int l32 = lane & 31;
    const int lh  = lane >> 5;                      // 16B k-chunk within 32B

    const char* aB = Xb + (size_t)(bi * 64 + l32) * 128 + lh * 16;
    const char* bB = Xb + (size_t)(bj * 64 + l32) * 128 + lh * 16;

    // ---- issue all 16 fragment loads, ks-major (earliest-needed first) ----
    i32x4 a[2][4], b[2][4];
#pragma unroll
    for (int ks = 0; ks < 4; ++ks) {
        a[0][ks] = *reinterpret_cast<const i32x4*>(aB + ks * 32);
        a[1][ks] = *reinterpret_cast<const i32x4*>(aB + 32 * 128 + ks * 32);
        b[0][ks] = *reinterpret_cast<const i32x4*>(bB + ks * 32);
        b[1][ks] = *reinterpret_cast<const i32x4*>(bB + 32 * 128 + ks * 32);
    }

    i32x16 acc[2][2];
#pragma unroll
    for (int mi = 0; mi < 2; ++mi)
#pragma unroll
        for (int ni = 0; ni < 2; ++ni)
#pragma unroll
            for (int e = 0; e < 16; ++e)
                acc[mi][ni][e] = 0;

    // ---- MFMA: consume in issue order; compiler inserts counted vmcnt ----
#pragma unroll
    for (int ks = 0; ks < 4; ++ks)
#pragma unroll
        for (int mi = 0; mi < 2; ++mi)
#pragma unroll
            for (int ni = 0; ni < 2; ++ni)
                acc[mi][ni] = __builtin_amdgcn_mfma_i32_32x32x32_i8(
                    a[mi][ks], b[ni][ks], acc[mi][ni], 0, 0, 0);

    // ---- epilogue: dot = v/127^2; sum exp2(C1*dot - C1) == exp(-2*d^2) ----
    const float C1  = 4.0f * 1.4426950408889634f;   // 4*log2(e)
    const float C1s = C1 / 16129.0f;
    float s0 = 0.f, s1 = 0.f, s2 = 0.f, s3 = 0.f;
#pragma unroll
    for (int mi = 0; mi < 2; ++mi)
#pragma unroll
        for (int ni = 0; ni < 2; ++ni) {
            const i32x16 v = acc[mi][ni];
#pragma unroll
            for (int e = 0; e < 16; e += 4) {
                s0 += fast_exp2(fmaf((float)v[e + 0], C1s, -C1));
                s1 += fast_exp2(fmaf((float)v[e + 1], C1s, -C1));
                s2 += fast_exp2(fmaf((float)v[e + 2], C1s, -C1));
                s3 += fast_exp2(fmaf((float)v[e + 3], C1s, -C1));
            }
        }

    float s = (s0 + s1) + (s2 + s3);
    for (int off = 32; off; off >>= 1) s += __shfl_xor(s, off, 64);

    if (lane == 0) {
        double bs = (double)s;
        if (bi != bj) bs *= 2.0;     // off-diagonal tile counts twice in S_full
        Spart[wid] = bs;
    }
}

// ---------------------------------------------------------------------------
// Kernel 3: final reduction + loss formula. One block, 1024 threads.
// ---------------------------------------------------------------------------
__global__ __launch_bounds__(1024) void finalize_kernel(
    const double* __restrict__ alignPart, const double* __restrict__ Spart,
    float* __restrict__ out)
{
    const int tid = threadIdx.x;
    double a = 0.0, su = 0.0, sp = 0.0;
    for (int i = tid; i < 1024; i += 1024) a += alignPart[i];
    for (int i = tid; i < 2 * JOBSW; i += 1024) {
        const double v = Spart[i];
        if (i < JOBSW) su += v; else sp += v;
    }
    for (int off = 32; off; off >>= 1) {
        a  += __shfl_xor(a,  off, 64);
        su += __shfl_xor(su, off, 64);
        sp += __shfl_xor(sp, off, 64);
    }
    __shared__ double sh[3][16];
    const int lane = tid & 63, wid = tid >> 6;
    if (lane == 0) { sh[0][wid] = a; sh[1][wid] = su; sh[2][wid] = sp; }
    __syncthreads();
    if (tid == 0) {
        double A = 0.0, SU = 0.0, SP = 0.0;
        for (int i = 0; i < 16; ++i) { A += sh[0][i]; SU += sh[1][i]; SP += sh[2][i]; }
        const double Nd = 8192.0;
        const double npairs = Nd * (Nd - 1.0) * 0.5;
        const double align = A / Nd;
        const double mu = (SU - Nd) * 0.5 / npairs;
        const double mp = (SP - Nd) * 0.5 / npairs;
        const double uniform = 0.25 * (log(mu) + log(mp));
        out[0] = (float)((align + uniform) / 8192.0);
    }
}

// ---------------------------------------------------------------------------
extern "C" void kernel_launch(void* const* d_in, const int* in_sizes, int n_in,
                              void* d_out, int out_size, void* d_ws, size_t ws_size,
                              hipStream_t stream)
{
    const float* users = (const float*)d_in[0];
    const float* pos   = (const float*)d_in[1];
    // d_in[2] (neg_items) intentionally unused, matching the reference.
    float* out = (float*)d_out;

    char* ws = (char*)d_ws;
    signed char* U8 = (signed char*)ws;                    // 1 MiB
    signed char* P8 = (signed char*)(ws + 1048576);        // 1 MiB
    double* alignPart = (double*)(ws + 2097152);           // 1024 doubles
    double* Spart     = (double*)(ws + 2097152 + 8192);    // 16512 doubles

    hipLaunchKernelGGL(prep_kernel, dim3(1024), dim3(256), 0, stream,
                       users, pos, U8, P8, alignPart);
    hipLaunchKernelGGL(gram_kernel, dim3(2 * JOBSW / 4), dim3(256), 0, stream,
                       U8, P8, Spart);
    hipLaunchKernelGGL(finalize_kernel, dim3(1), dim3(1024), 0, stream,
                       alignPart, Spart, out);
}

// Round 13
// 36.915 us; speedup vs baseline: 1.3766x; 1.3766x over previous
//
#include <hip/hip_runtime.h>
#include <hip/hip_bf16.h>

typedef int   i32x4  __attribute__((ext_vector_type(4)));
typedef int   i32x16 __attribute__((ext_vector_type(16)));

#define NROWS 8192
#define DIM   128
#define NB    64            // 8192 / 128 row-blocks
#define JOBS_PER_MAT 2080   // 64*65/2 upper-tri incl diag

__device__ __forceinline__ float fast_exp2(float x) {
    return __builtin_amdgcn_exp2f(x);
}

// async global->LDS, 16B per lane; lds dest is wave-uniform base (+lane*16 by HW)
__device__ __forceinline__ void gload16(const void* g, void* l) {
    __builtin_amdgcn_global_load_lds(
        (const __attribute__((address_space(1))) unsigned int*)(uintptr_t)g,
        (__attribute__((address_space(3))) unsigned int*)(uintptr_t)l,
        16, 0, 0);
}

__device__ __forceinline__ int tri(int b) { return b * NB - (b * (b - 1)) / 2; }

// ---------------------------------------------------------------------------
// Kernel 1: normalize rows (float4, 2 rows/wave), align partials (exact fp32),
// emit i8 quantized normalized rows: q = round(127 * x_hat).
// ---------------------------------------------------------------------------
__global__ __launch_bounds__(256) void prep_kernel(
    const float* __restrict__ users, const float* __restrict__ pos,
    signed char* __restrict__ U8, signed char* __restrict__ P8,
    double* __restrict__ alignPart)
{
    const int tid  = threadIdx.x;
    const int lane = tid & 63;
    const int w    = tid >> 6;
    const int l32  = lane & 31;
    const int half = lane >> 5;
    const int r    = blockIdx.x * 8 + w * 2 + half;

    const float4 u4 = ((const float4*)users)[r * 32 + l32];
    const float4 p4 = ((const float4*)pos )[r * 32 + l32];

    float su = u4.x*u4.x + u4.y*u4.y + u4.z*u4.z + u4.w*u4.w;
    float sp = p4.x*p4.x + p4.y*p4.y + p4.z*p4.z + p4.w*p4.w;
    for (int off = 16; off; off >>= 1) {
        su += __shfl_xor(su, off, 64);
        sp += __shfl_xor(sp, off, 64);
    }
    const float nu  = fmaxf(sqrtf(su), 1e-12f);
    const float npp = fmaxf(sqrtf(sp), 1e-12f);

    const float ux = u4.x / nu,  uy = u4.y / nu,  uz = u4.z / nu,  uw = u4.w / nu;
    const float px = p4.x / npp, py = p4.y / npp, pz = p4.z / npp, pw = p4.w / npp;

    union { signed char c[4]; int i; } qu, qp;
    qu.c[0] = (signed char)__float2int_rn(ux * 127.0f);
    qu.c[1] = (signed char)__float2int_rn(uy * 127.0f);
    qu.c[2] = (signed char)__float2int_rn(uz * 127.0f);
    qu.c[3] = (signed char)__float2int_rn(uw * 127.0f);
    qp.c[0] = (signed char)__float2int_rn(px * 127.0f);
    qp.c[1] = (signed char)__float2int_rn(py * 127.0f);
    qp.c[2] = (signed char)__float2int_rn(pz * 127.0f);
    qp.c[3] = (signed char)__float2int_rn(pw * 127.0f);
    ((int*)U8)[r * 32 + l32] = qu.i;
    ((int*)P8)[r * 32 + l32] = qp.i;

    const float dx = ux - px, dy = uy - py, dz = uz - pz, dw = uw - pw;
    float al = dx*dx + dy*dy + dz*dz + dw*dw;
    for (int off = 16; off; off >>= 1) al += __shfl_xor(al, off, 64);
    al += __shfl_xor(al, 32, 64);

    __shared__ float wsum[4];
    if (lane == 0) wsum[w] = al;
    __syncthreads();
    if (tid == 0)
        alignPart[blockIdx.x] = (double)wsum[0] + (double)wsum[1]
                              + (double)wsum[2] + (double)wsum[3];
}

// ---------------------------------------------------------------------------
// Kernel 2: 128x128 tile per block (bi<=bj, off-diag x2), i8.
//   A-operand: REGISTERS (8 x dwordx4 per lane from L2; identical (row,k)
//   mapping as the LDS path, so operands — and the Gram sum — are unchanged).
//   Loads issued first, then pinned with an empty asm "+v" barrier so the
//   compiler cannot re-sink them into the MFMA loop (R8's failure mode).
//   B-operand: 16KB LDS, staged once per job via global_load_lds.
//   Swizzle (verified R9): rows 128B = 8 chunks of 16B; LDS chunk c of row r
//   holds global chunk c^(r&7) (pre-swizzled source, linear dest; reads XOR).
//   4 waves (2x2), wave tile 64x64 = 2x2 mfma_i32_32x32x32_i8.
//   __launch_bounds__(256,3): VGPR<=170 (est ~135) -> 3 blocks/CU, 12 waves.
// ---------------------------------------------------------------------------
__global__ __launch_bounds__(256, 3) void gram_kernel(
    const signed char* __restrict__ U8, const signed char* __restrict__ P8,
    double* __restrict__ Spart)
{
    __shared__ __align__(16) unsigned char smem[16384];
    __shared__ float wsum[4];

    const int bid = blockIdx.x;
    const int mat = bid >= JOBS_PER_MAT;
    const int t   = bid - (mat ? JOBS_PER_MAT : 0);

    int bi = (int)((NB + 0.5f) - sqrtf((NB + 0.5f) * (NB + 0.5f) - 2.0f * (float)t));
    if (bi > 0 && tri(bi) > t) --bi;
    if (tri(bi + 1) <= t) ++bi;
    const int bj = bi + (t - tri(bi));

    const char* __restrict__ Xb = (const char*)(mat ? P8 : U8);

    const int tid  = threadIdx.x;
    const int lane = tid & 63;
    const int w    = tid >> 6;
    const int wm = w >> 1, wn = w & 1;
    const int l32 = lane & 31;
    const int lh  = lane >> 5;                       // 16B k-chunk select

    // ---- A fragments -> registers (issued first; pinned below) ----
    const char* aBase = Xb + (size_t)(bi * 128 + wm * 64 + l32) * 128 + lh * 16;
    i32x4 a[2][4];
#pragma unroll
    for (int mi = 0; mi < 2; ++mi)
#pragma unroll
        for (int ks = 0; ks < 4; ++ks)
            a[mi][ks] = *reinterpret_cast<const i32x4*>(
                aBase + mi * 32 * 128 + ks * 32);

    // ---- B staging: thread covers rows (tid>>3)+32i, linear chunk tid&7;
    //      global chunk pre-swizzled ^(row&7) ((tid>>3)&7 invariant in i). ----
    const int srow  = tid >> 3;                      // 0..31
    const int gcOff = (((tid & 7) ^ (srow & 7)) << 4);
    unsigned char* lB0 = smem + w * 1024;            // wave-uniform dest base
#pragma unroll
    for (int i = 0; i < 4; ++i)                      // 4 passes x 4KB
        gload16(Xb + (size_t)(bj * 128 + srow + 32 * i) * 128 + gcOff,
                lB0 + i * 4096);

    // pin A in registers: compiler may not rematerialize/sink these loads
#pragma unroll
    for (int mi = 0; mi < 2; ++mi)
#pragma unroll
        for (int ks = 0; ks < 4; ++ks)
            asm volatile("" : "+v"(a[mi][ks]));

    i32x16 acc[2][2];
#pragma unroll
    for (int mi = 0; mi < 2; ++mi)
#pragma unroll
        for (int ni = 0; ni < 2; ++ni)
#pragma unroll
            for (int e = 0; e < 16; ++e)
                acc[mi][ni][e] = 0;

    __syncthreads();   // B staged (barrier implies vmcnt(0) drain)

    // ---- MFMA: B from LDS (8 ds_read_b128/lane), A from regs ----
    const unsigned bRow0 = (unsigned)(wn * 64 + l32);
    const unsigned cxor  = (unsigned)(l32 & 7);
#pragma unroll
    for (int ks = 0; ks < 4; ++ks) {
        const unsigned c = (((unsigned)(ks * 2 + lh)) ^ cxor) << 4;
        i32x4 b[2];
#pragma unroll
        for (int ni = 0; ni < 2; ++ni)
            b[ni] = *reinterpret_cast<const i32x4*>(
                smem + (bRow0 + ni * 32) * 128 + c);
#pragma unroll
        for (int mi = 0; mi < 2; ++mi)
#pragma unroll
            for (int ni = 0; ni < 2; ++ni)
                acc[mi][ni] = __builtin_amdgcn_mfma_i32_32x32x32_i8(
                    a[mi][ks], b[ni], acc[mi][ni], 0, 0, 0);
    }

    // ---- epilogue: dot = v/127^2; sum exp2(C1*dot - C1) == exp(-2*d^2) ----
    const float C1  = 4.0f * 1.4426950408889634f;    // 4*log2(e)
    const float C1s = C1 / 16129.0f;
    float s0 = 0.f, s1 = 0.f, s2 = 0.f, s3 = 0.f;
#pragma unroll
    for (int mi = 0; mi < 2; ++mi)
#pragma unroll
        for (int ni = 0; ni < 2; ++ni) {
            const i32x16 v = acc[mi][ni];
#pragma unroll
            for (int e = 0; e < 16; e += 4) {
                s0 += fast_exp2(fmaf((float)v[e + 0], C1s, -C1));
                s1 += fast_exp2(fmaf((float)v[e + 1], C1s, -C1));
                s2 += fast_exp2(fmaf((float)v[e + 2], C1s, -C1));
                s3 += fast_exp2(fmaf((float)v[e + 3], C1s, -C1));
            }
        }

    float s = (s0 + s1) + (s2 + s3);
    for (int off = 32; off; off >>= 1) s += __shfl_xor(s, off, 64);
    if (lane == 0) wsum[w] = s;
    __syncthreads();
    if (tid == 0) {
        double bs = (double)wsum[0] + (double)wsum[1]
                  + (double)wsum[2] + (double)wsum[3];
        if (bi != bj) bs *= 2.0;     // off-diagonal tile counts twice in S_full
        Spart[bid] = bs;
    }
}

// ---------------------------------------------------------------------------
// Kernel 3: final reduction + loss formula. One block, 1024 threads.
// ---------------------------------------------------------------------------
__global__ __launch_bounds__(1024) void finalize_kernel(
    const double* __restrict__ alignPart, const double* __restrict__ Spart,
    float* __restrict__ out)
{
    const int tid = threadIdx.x;
    double a = 0.0, su = 0.0, sp = 0.0;
    for (int i = tid; i < 1024; i += 1024) a += alignPart[i];
    for (int i = tid; i < 2 * JOBS_PER_MAT; i += 1024) {
        const double v = Spart[i];
        if (i < JOBS_PER_MAT) su += v; else sp += v;
    }
    for (int off = 32; off; off >>= 1) {
        a  += __shfl_xor(a,  off, 64);
        su += __shfl_xor(su, off, 64);
        sp += __shfl_xor(sp, off, 64);
    }
    __shared__ double sh[3][16];
    const int lane = tid & 63, wid = tid >> 6;
    if (lane == 0) { sh[0][wid] = a; sh[1][wid] = su; sh[2][wid] = sp; }
    __syncthreads();
    if (tid == 0) {
        double A = 0.0, SU = 0.0, SP = 0.0;
        for (int i = 0; i < 16; ++i) { A += sh[0][i]; SU += sh[1][i]; SP += sh[2][i]; }
        const double Nd = 8192.0;
        const double npairs = Nd * (Nd - 1.0) * 0.5;
        const double align = A / Nd;
        const double mu = (SU - Nd) * 0.5 / npairs;
        const double mp = (SP - Nd) * 0.5 / npairs;
        const double uniform = 0.25 * (log(mu) + log(mp));
        out[0] = (float)((align + uniform) / 8192.0);
    }
}

// ---------------------------------------------------------------------------
extern "C" void kernel_launch(void* const* d_in, const int* in_sizes, int n_in,
                              void* d_out, int out_size, void* d_ws, size_t ws_size,
                              hipStream_t stream)
{
    const float* users = (const float*)d_in[0];
    const float* pos   = (const float*)d_in[1];
    // d_in[2] (neg_items) intentionally unused, matching the reference.
    float* out = (float*)d_out;

    char* ws = (char*)d_ws;
    signed char* U8 = (signed char*)ws;                    // 1 MiB
    signed char* P8 = (signed char*)(ws + 1048576);        // 1 MiB
    double* alignPart = (double*)(ws + 2097152);           // 1024 doubles
    double* Spart     = (double*)(ws + 2097152 + 8192);    // 4160 doubles

    hipLaunchKernelGGL(prep_kernel, dim3(1024), dim3(256), 0, stream,
                       users, pos, U8, P8, alignPart);
    hipLaunchKernelGGL(gram_kernel, dim3(2 * JOBS_PER_MAT), dim3(256), 0, stream,
                       U8, P8, Spart);
    hipLaunchKernelGGL(finalize_kernel, dim3(1), dim3(1024), 0, stream,
                       alignPart, Spart, out);
}